// Round 10
// baseline (335.901 us; speedup 1.0000x reference)
//
#include <hip/hip_runtime.h>
#include <hip/hip_bf16.h>
#include <cstdint>
#include <cstddef>

// B=4, T=2048, D=768, H=12, DH=64. SCALE=8*log2(e) folded into Q at QKV time.
#define Bsz 4
#define Tsz 2048
#define Dsz 768
#define Hsz 12
#define DHsz 64
#define Msz (Bsz * Tsz)   // 8192
#define K2 1536           // stored K width of [hi|lo] buffers
#define QSCALE 11.5415603f  // 8 * log2(e): softmax via exp2

typedef __attribute__((ext_vector_type(8))) short short8;
typedef __attribute__((ext_vector_type(4))) float floatx4;

#if __has_builtin(__builtin_amdgcn_exp2f)
#define EXP2(x) __builtin_amdgcn_exp2f(x)
#else
#define EXP2(x) exp2f(x)
#endif

typedef const __attribute__((address_space(1))) unsigned int* gas1;
typedef __attribute__((address_space(3))) unsigned int* las3;
// async global->LDS DMA, 16 B/lane, lane i lands at ldsbase + 16*i (wave-linear)
__device__ __forceinline__ void dma16(const unsigned short* g, unsigned short* l) {
  __builtin_amdgcn_global_load_lds((gas1)g, (las3)l, 16, 0, 0);
}

__device__ __forceinline__ unsigned short f2bf(float f) {
  union { float f; unsigned u; } v; v.f = f;
  unsigned u = v.u;
  unsigned r = u + 0x7fffu + ((u >> 16) & 1u);  // RNE; finite inputs
  return (unsigned short)(r >> 16);
}
__device__ __forceinline__ float bf2f(unsigned short h) {
  union { unsigned u; float f; } v; v.u = ((unsigned)h) << 16; return v.f;
}
__device__ __forceinline__ unsigned pk_bf2(float a, float b) {
  union { __hip_bfloat162 b2; unsigned u; } cv;
  cv.b2 = __float22bfloat162_rn(make_float2(a, b));  // v_cvt_pk_bf16_f32
  return cv.u;
}

// XOR-swizzled tile addressing: tile stored as [rows][8 granules of 8 shorts],
// physical granule = g ^ (row&7). DMA writes linear; reads swizzle. 0 conflicts (R6).
#define TREAD(arr, row, s) \
  (*reinterpret_cast<const short8*>(&(arr)[((row) << 6) + ((((s) * 4 + quad) ^ ((row) & 7)) << 3)]))

// ---------------- split kernels: f32 -> row-interleaved [hi768|lo768] ----------------
__global__ void split_x(const float* __restrict__ src,
                        unsigned short* __restrict__ dst) {
  int i = (blockIdx.x * blockDim.x + threadIdx.x) * 4;   // exact cover of Msz*Dsz
  int row = i / Dsz, col = i % Dsz;
  float4 v = *reinterpret_cast<const float4*>(src + i);
  ushort4 h, l;
  h.x = f2bf(v.x); l.x = f2bf(v.x - bf2f(h.x));
  h.y = f2bf(v.y); l.y = f2bf(v.y - bf2f(h.y));
  h.z = f2bf(v.z); l.z = f2bf(v.z - bf2f(h.z));
  h.w = f2bf(v.w); l.w = f2bf(v.w - bf2f(h.w));
  unsigned short* base = dst + (size_t)row * K2 + col;
  *reinterpret_cast<ushort4*>(base) = h;
  *reinterpret_cast<ushort4*>(base + Dsz) = l;
}

// w_qkv [2304][768] -> permuted rows r' = kk*768 + h*64 + d (src row d*36+kk*12+h),
// row-interleaved [hi768|lo768]
__global__ void split_w(const float* __restrict__ src,
                        unsigned short* __restrict__ dst) {
  int i = (blockIdx.x * blockDim.x + threadIdx.x) * 4;   // exact cover of 3*Dsz*Dsz
  int rp = i / Dsz, c = i % Dsz;
  int kk = rp / Dsz;
  int rem = rp - kk * Dsz;
  int h = rem >> 6, d = rem & 63;
  const float* s = src + (size_t)(d * 36 + kk * 12 + h) * Dsz + c;
  float4 v = *reinterpret_cast<const float4*>(s);
  ushort4 hh, ll;
  hh.x = f2bf(v.x); ll.x = f2bf(v.x - bf2f(hh.x));
  hh.y = f2bf(v.y); ll.y = f2bf(v.y - bf2f(hh.y));
  hh.z = f2bf(v.z); ll.z = f2bf(v.z - bf2f(hh.z));
  hh.w = f2bf(v.w); ll.w = f2bf(v.w - bf2f(hh.w));
  unsigned short* base = dst + (size_t)rp * K2 + c;
  *reinterpret_cast<ushort4*>(base) = hh;
  *reinterpret_cast<ushort4*>(base + Dsz) = ll;
}

__global__ void cvt_f32_bf16(const float* __restrict__ src,
                             unsigned short* __restrict__ dst, int n) {
  int i = (blockIdx.x * blockDim.x + threadIdx.x) * 4;
  int stride = gridDim.x * blockDim.x * 4;
  for (; i < n; i += stride) {
    float4 v = *reinterpret_cast<const float4*>(src + i);
    ushort4 o;
    o.x = f2bf(v.x); o.y = f2bf(v.y); o.z = f2bf(v.z); o.w = f2bf(v.w);
    *reinterpret_cast<ushort4*>(dst + i) = o;
  }
}

// ---------------- QKV GEMM: A-direct (per-wave rows), B in LDS ----------------
// Q/K: Xh.Wh + Xh.Wl + Xl.Wh; V: Xh.Wh only. 128x64 tiles, grid (36,64) N-fastest.
// A-fragments are wave-exclusive -> direct global loads (compiler pipelines);
// only the cross-wave-shared B tile is DMA-staged (16 KB/iter).
__launch_bounds__(256, 4)
__global__ void gemm_qkv(const unsigned short* __restrict__ xs,
                         const unsigned short* __restrict__ wsb,
                         unsigned short* __restrict__ Qhp,
                         unsigned short* __restrict__ Qlp,
                         unsigned short* __restrict__ Khp,
                         unsigned short* __restrict__ Klp,
                         unsigned short* __restrict__ Vtp) {
  __shared__ unsigned short Bh[64 * 64], Bl[64 * 64];    // 8 KB each, swizzled
  const int nblk = blockIdx.x;      // 0..35  (FAST dim: A-tile shared by neighbors)
  const int mt128 = blockIdx.y;     // 0..63
  const int kk = nblk / 12;         // 0:Q 1:K 2:V
  const int h  = nblk % 12;
  const int tid = threadIdx.x;
  const int w = tid >> 6, lane = tid & 63, l16 = lane & 15, quad = lane >> 4;
  const int lrow = lane >> 3;              // 0..7
  const int lgl  = (lane & 7) ^ lrow;      // XOR granule

  floatx4 acc[2][4];
#pragma unroll
  for (int mt = 0; mt < 2; ++mt)
#pragma unroll
    for (int nt = 0; nt < 4; ++nt) acc[mt][nt] = (floatx4){0.f, 0.f, 0.f, 0.f};

  // A-frag base addresses (hi at +0, lo at +Dsz): row = mt128*128 + w*32 + mt*16 + l16
  const unsigned short* aptr[2];
#pragma unroll
  for (int mt = 0; mt < 2; ++mt)
    aptr[mt] = xs + (size_t)(mt128 * 128 + w * 32 + mt * 16 + l16) * K2 + quad * 8;
  const size_t bbase = (size_t)(kk * Dsz + h * 64) * K2;

  for (int kc = 0; kc < Dsz; kc += 64) {
    // A-fragments direct from global (registers; latency hidden by barrier+DMA below)
    short8 ah[2][2], al[2][2];
#pragma unroll
    for (int mt = 0; mt < 2; ++mt)
#pragma unroll
      for (int s = 0; s < 2; ++s) {
        ah[mt][s] = *reinterpret_cast<const short8*>(aptr[mt] + kc + s * 32);
        if (kk != 2)
          al[mt][s] = *reinterpret_cast<const short8*>(aptr[mt] + kc + s * 32 + Dsz);
      }
    __syncthreads();   // prev iter's B readers done
#pragma unroll
    for (int j = 0; j < 2; ++j) {          // B: 8 KB (+8 KB lo), 2(+2) insts/wave
      const int R0 = w * 16 + j * 8;
      const size_t g = bbase + (size_t)(R0 + lrow) * K2 + kc + lgl * 8;
      dma16(wsb + g, &Bh[R0 * 64]);
      if (kk != 2) dma16(wsb + g + Dsz, &Bl[R0 * 64]);
    }
    __syncthreads();   // vmcnt drain: B visible
#pragma unroll
    for (int s = 0; s < 2; ++s) {
#pragma unroll
      for (int nt = 0; nt < 4; ++nt) {
        short8 bh = TREAD(Bh, nt * 16 + l16, s);
#pragma unroll
        for (int mt = 0; mt < 2; ++mt)
          acc[mt][nt] = __builtin_amdgcn_mfma_f32_16x16x32_bf16(ah[mt][s], bh, acc[mt][nt], 0, 0, 0);
        if (kk != 2) {
          short8 bl = TREAD(Bl, nt * 16 + l16, s);
#pragma unroll
          for (int mt = 0; mt < 2; ++mt) {
            acc[mt][nt] = __builtin_amdgcn_mfma_f32_16x16x32_bf16(ah[mt][s], bl, acc[mt][nt], 0, 0, 0);
            acc[mt][nt] = __builtin_amdgcn_mfma_f32_16x16x32_bf16(al[mt][s], bh, acc[mt][nt], 0, 0, 0);
          }
        }
      }
    }
  }
#pragma unroll
  for (int mt = 0; mt < 2; ++mt) {
    const int mbase = mt128 * 128 + w * 32 + mt * 16 + quad * 4;
    const int b = mbase >> 11;   // tiles never cross batch boundary
    const size_t hoff = (size_t)(b * Hsz + h) * Tsz * DHsz;
    const int t0 = mbase & (Tsz - 1);
    if (kk == 2) {
      unsigned short* dst = Vtp + hoff;   // [dh][t]
#pragma unroll
      for (int nt = 0; nt < 4; ++nt) {
        int d = nt * 16 + l16;
        uint2 pk;
        pk.x = pk_bf2(acc[mt][nt][0], acc[mt][nt][1]);
        pk.y = pk_bf2(acc[mt][nt][2], acc[mt][nt][3]);
        *reinterpret_cast<uint2*>(&dst[(size_t)d * Tsz + t0]) = pk;
      }
    } else {
      const float sc = (kk == 0) ? QSCALE : 1.0f;   // fold 8*log2e into Q
      unsigned short* dh_ = ((kk == 0) ? Qhp : Khp) + hoff;
      unsigned short* dl_ = ((kk == 0) ? Qlp : Klp) + hoff;
#pragma unroll
      for (int nt = 0; nt < 4; ++nt) {
        int d = nt * 16 + l16;
#pragma unroll
        for (int r = 0; r < 4; ++r) {
          float v = acc[mt][nt][r] * sc;
          unsigned short hv = f2bf(v);
          dh_[(size_t)(t0 + r) * DHsz + d] = hv;
          dl_[(size_t)(t0 + r) * DHsz + d] = f2bf(v - bf2f(hv));
        }
      }
    }
  }
}

// ---------------- fused flash attention (R8/R9-verified, ~119 us) ----------------
__launch_bounds__(256, 3)
__global__ void attn(const unsigned short* __restrict__ Qhp,
                     const unsigned short* __restrict__ Qlp,
                     const unsigned short* __restrict__ Khp,
                     const unsigned short* __restrict__ Klp,
                     const unsigned short* __restrict__ Vtp,
                     unsigned short* __restrict__ Ob) {
  __shared__ unsigned short Ksh[64 * 64], Ksl[64 * 64], Vs[64 * 64];  // swizzled tiles
  __shared__ unsigned short plT[4][2][16][68];   // 68-pad: proven 0-conflict writes
  const int bid = blockIdx.x;          // 0..767
  const int xcd = bid & 7, slot = bid >> 3;
  const int bh = xcd * 6 + (slot >> 4);
  const int qt = slot & 15;
  const int tid = threadIdx.x;
  const int w = tid >> 6, lane = tid & 63, l16 = lane & 15, quad = lane >> 4;
  const int lrow = lane >> 3;
  const int lgl  = (lane & 7) ^ lrow;
  const size_t hoff = (size_t)bh * Tsz * DHsz;
  const unsigned short* Kh = Khp + hoff;
  const unsigned short* Kl = Klp + hoff;
  const unsigned short* Vt = Vtp + hoff;   // [dh][t]

  // Q B-frags (pre-scaled by 8*log2e)
  short8 qh[2][2], ql[2][2];
#pragma unroll
  for (int mt = 0; mt < 2; ++mt) {
    const size_t qoff = hoff + (size_t)(qt * 128 + w * 32 + mt * 16 + l16) * DHsz + quad * 8;
    qh[mt][0] = *reinterpret_cast<const short8*>(Qhp + qoff);
    qh[mt][1] = *reinterpret_cast<const short8*>(Qhp + qoff + 32);
    ql[mt][0] = *reinterpret_cast<const short8*>(Qlp + qoff);
    ql[mt][1] = *reinterpret_cast<const short8*>(Qlp + qoff + 32);
  }

  floatx4 Of[2][4];
#pragma unroll
  for (int mt = 0; mt < 2; ++mt)
#pragma unroll
    for (int nt = 0; nt < 4; ++nt) Of[mt][nt] = (floatx4){0.f, 0.f, 0.f, 0.f};
  float m_i[2] = {-1e30f, -1e30f};
  float l_i[2] = {0.f, 0.f};

  for (int kt = 0; kt < Tsz; kt += 64) {
    __syncthreads();   // prev tile's readers done
#pragma unroll
    for (int j = 0; j < 2; ++j) {       // each array 8 KB = 2 insts/wave
      const int R0 = w * 16 + j * 8;
      dma16(Kh + (size_t)(kt + R0 + lrow) * DHsz + lgl * 8, &Ksh[R0 * 64]);
      dma16(Kl + (size_t)(kt + R0 + lrow) * DHsz + lgl * 8, &Ksl[R0 * 64]);
      dma16(Vt + (size_t)(R0 + lrow) * Tsz + kt + lgl * 8,  &Vs[R0 * 64]);
    }
    __syncthreads();   // vmcnt drain: staged tiles visible

    // S^T = K Q^T, double-bf16 (Kh*Qh + Kl*Qh + Kh*Ql)
    floatx4 S[2][4];
#pragma unroll
    for (int mt = 0; mt < 2; ++mt)
#pragma unroll
      for (int nt = 0; nt < 4; ++nt) S[mt][nt] = (floatx4){0.f, 0.f, 0.f, 0.f};
#pragma unroll
    for (int s = 0; s < 2; ++s) {
#pragma unroll
      for (int nt = 0; nt < 4; ++nt) {
        short8 kf_h = TREAD(Ksh, nt * 16 + l16, s);
        short8 kf_l = TREAD(Ksl, nt * 16 + l16, s);
        S[0][nt] = __builtin_amdgcn_mfma_f32_16x16x32_bf16(kf_h, qh[0][s], S[0][nt], 0, 0, 0);
        S[0][nt] = __builtin_amdgcn_mfma_f32_16x16x32_bf16(kf_l, qh[0][s], S[0][nt], 0, 0, 0);
        S[0][nt] = __builtin_amdgcn_mfma_f32_16x16x32_bf16(kf_h, ql[0][s], S[0][nt], 0, 0, 0);
        S[1][nt] = __builtin_amdgcn_mfma_f32_16x16x32_bf16(kf_h, qh[1][s], S[1][nt], 0, 0, 0);
        S[1][nt] = __builtin_amdgcn_mfma_f32_16x16x32_bf16(kf_l, qh[1][s], S[1][nt], 0, 0, 0);
        S[1][nt] = __builtin_amdgcn_mfma_f32_16x16x32_bf16(kf_h, ql[1][s], S[1][nt], 0, 0, 0);
      }
    }

    // per-lane online softmax in exp2 domain (q = l16; keys in regs+quads)
#pragma unroll
    for (int mt = 0; mt < 2; ++mt) {
      float mx = -1e30f;
#pragma unroll
      for (int nt = 0; nt < 4; ++nt)
#pragma unroll
        for (int r = 0; r < 4; ++r) mx = fmaxf(mx, S[mt][nt][r]);
      mx = fmaxf(mx, __shfl_xor(mx, 16));
      mx = fmaxf(mx, __shfl_xor(mx, 32));
      float mnew = fmaxf(m_i[mt], mx);
      float alpha = EXP2(m_i[mt] - mnew);
      m_i[mt] = mnew;
      float ls = 0.f;
#pragma unroll
      for (int nt = 0; nt < 4; ++nt) {
        float p0 = EXP2(S[mt][nt][0] - mnew);
        float p1 = EXP2(S[mt][nt][1] - mnew);
        float p2 = EXP2(S[mt][nt][2] - mnew);
        float p3 = EXP2(S[mt][nt][3] - mnew);
        ls += (p0 + p1) + (p2 + p3);
        uint2 pk;
        pk.x = pk_bf2(p0, p1);
        pk.y = pk_bf2(p2, p3);
        *reinterpret_cast<uint2*>(&plT[w][mt][l16][nt * 16 + quad * 4]) = pk;
      }
      l_i[mt] = l_i[mt] * alpha + ls;
#pragma unroll
      for (int nt = 0; nt < 4; ++nt) {
        Of[mt][nt][0] *= alpha; Of[mt][nt][1] *= alpha;
        Of[mt][nt][2] *= alpha; Of[mt][nt][3] *= alpha;
      }
    }

    // O^T += V^T @ P^T (wave-local LDS RAW; wave-synchronous)
    short8 pf[2][2];
#pragma unroll
    for (int s = 0; s < 2; ++s) {
      pf[0][s] = *reinterpret_cast<const short8*>(&plT[w][0][l16][s * 32 + quad * 8]);
      pf[1][s] = *reinterpret_cast<const short8*>(&plT[w][1][l16][s * 32 + quad * 8]);
    }
#pragma unroll
    for (int nt = 0; nt < 4; ++nt) {
#pragma unroll
      for (int s = 0; s < 2; ++s) {
        short8 vf = TREAD(Vs, nt * 16 + l16, s);
        Of[0][nt] = __builtin_amdgcn_mfma_f32_16x16x32_bf16(vf, pf[0][s], Of[0][nt], 0, 0, 0);
        Of[1][nt] = __builtin_amdgcn_mfma_f32_16x16x32_bf16(vf, pf[1][s], Of[1][nt], 0, 0, 0);
      }
    }
  }

  // epilogue: O[b][t][h*64+dh]; dh = nt*16 + quad*4 + reg, t = ... + l16
  const int b = bh / Hsz, h = bh % Hsz;
#pragma unroll
  for (int mt = 0; mt < 2; ++mt) {
    float ls = l_i[mt];
    ls += __shfl_xor(ls, 16);
    ls += __shfl_xor(ls, 32);
    float inv = 1.0f / ls;
    int t = qt * 128 + w * 32 + mt * 16 + l16;
    unsigned short* orow = Ob + (size_t)(b * Tsz + t) * Dsz + h * DHsz;
#pragma unroll
    for (int nt = 0; nt < 4; ++nt) {
      uint2 pk;
      pk.x = pk_bf2(Of[mt][nt][0] * inv, Of[mt][nt][1] * inv);
      pk.y = pk_bf2(Of[mt][nt][2] * inv, Of[mt][nt][3] * inv);
      *reinterpret_cast<uint2*>(&orow[nt * 16 + quad * 4]) = pk;
    }
  }
}

// ---------------- output GEMM: A-direct, B in LDS, 128x128 tiles ----------------
__launch_bounds__(256, 4)
__global__ void gemm_out(const unsigned short* __restrict__ ob,
                         const unsigned short* __restrict__ wb,
                         float* __restrict__ out) {
  __shared__ unsigned short Bs[128 * 64];   // 16 KB, swizzled
  const int n0 = blockIdx.x * 128;  // FAST dim: A-tile shared by neighbors
  const int mt128 = blockIdx.y;     // 0..63
  const int tid = threadIdx.x;
  const int w = tid >> 6, lane = tid & 63, l16 = lane & 15, quad = lane >> 4;
  const int lrow = lane >> 3;
  const int lgl  = (lane & 7) ^ lrow;

  floatx4 acc[2][8];
#pragma unroll
  for (int mt = 0; mt < 2; ++mt)
#pragma unroll
    for (int nt = 0; nt < 8; ++nt) acc[mt][nt] = (floatx4){0.f, 0.f, 0.f, 0.f};

  const unsigned short* aptr[2];
#pragma unroll
  for (int mt = 0; mt < 2; ++mt)
    aptr[mt] = ob + (size_t)(mt128 * 128 + w * 32 + mt * 16 + l16) * Dsz + quad * 8;
  const size_t bbase = (size_t)n0 * Dsz;

  for (int kc = 0; kc < Dsz; kc += 64) {
    short8 a[2][2];
#pragma unroll
    for (int mt = 0; mt < 2; ++mt)
#pragma unroll
      for (int s = 0; s < 2; ++s)
        a[mt][s] = *reinterpret_cast<const short8*>(aptr[mt] + kc + s * 32);
    __syncthreads();
#pragma unroll
    for (int j = 0; j < 4; ++j) {
      const int R0 = w * 32 + j * 8;
      dma16(wb + bbase + (size_t)(R0 + lrow) * Dsz + kc + lgl * 8, &Bs[R0 * 64]);
    }
    __syncthreads();
#pragma unroll
    for (int s = 0; s < 2; ++s) {
#pragma unroll
      for (int nt = 0; nt < 8; ++nt) {
        short8 b = TREAD(Bs, nt * 16 + l16, s);
#pragma unroll
        for (int mt = 0; mt < 2; ++mt)
          acc[mt][nt] = __builtin_amdgcn_mfma_f32_16x16x32_bf16(a[mt][s], b, acc[mt][nt], 0, 0, 0);
      }
    }
  }
#pragma unroll
  for (int mt = 0; mt < 2; ++mt) {
    const int mbase = mt128 * 128 + w * 32 + mt * 16 + quad * 4;
#pragma unroll
    for (int nt = 0; nt < 8; ++nt) {
      int n = n0 + nt * 16 + l16;
#pragma unroll
      for (int r = 0; r < 4; ++r) {
        out[(size_t)(mbase + r) * Dsz + n] = acc[mt][nt][r];
      }
    }
  }
}

// ---------------- launch ----------------
extern "C" void kernel_launch(void* const* d_in, const int* in_sizes, int n_in,
                              void* d_out, int out_size, void* d_ws, size_t ws_size,
                              hipStream_t stream) {
  const float* x     = (const float*)d_in[0];   // [4,2048,768]
  const float* w_qkv = (const float*)d_in[1];   // [2304,768]
  const float* w_out = (const float*)d_in[2];   // [768,768]
  float* out = (float*)d_out;                   // [4,2048,768]

  unsigned short* ws = (unsigned short*)d_ws;
  const size_t nXs = (size_t)Msz * K2;                // 12582912 (x hi|lo)
  const size_t nWs = (size_t)3 * Dsz * K2;            // 3538944 (w hi|lo)
  const size_t nWo = (size_t)Dsz * Dsz;               // 589824
  const size_t nHd = (size_t)Bsz * Hsz * Tsz * DHsz;  // 6291456

  unsigned short* xs  = ws;
  unsigned short* wsb = xs + nXs;
  unsigned short* wob = wsb + nWs;
  unsigned short* Qhp = wob + nWo;
  unsigned short* Qlp = Qhp + nHd;
  unsigned short* Khp = Qlp + nHd;
  unsigned short* Klp = Khp + nHd;
  unsigned short* Vtp = Klp + nHd;
  unsigned short* Ob  = xs;   // xs dead after gemm_qkv
  // peak ws use ~96.3 MB

  split_x<<<(int)(nXs / 2 / 1024), 256, 0, stream>>>(x, xs);
  split_w<<<(int)(nWs / 2 / 1024), 256, 0, stream>>>(w_qkv, wsb);
  cvt_f32_bf16<<<256, 256, 0, stream>>>(w_out, wob, (int)nWo);
  gemm_qkv<<<dim3(36, 64), 256, 0, stream>>>(xs, wsb, Qhp, Qlp, Khp, Klp, Vtp);
  attn<<<768, 256, 0, stream>>>(Qhp, Qlp, Khp, Klp, Vtp, Ob);
  gemm_out<<<dim3(6, 64), 256, 0, stream>>>(Ob, wob, out);
}

// Round 11
// 279.228 us; speedup vs baseline: 1.2030x; 1.2030x over previous
//
#include <hip/hip_runtime.h>
#include <hip/hip_bf16.h>
#include <cstdint>
#include <cstddef>

// B=4, T=2048, D=768, H=12, DH=64. SCALE=8*log2(e) folded into Q at QKV time.
#define Bsz 4
#define Tsz 2048
#define Dsz 768
#define Hsz 12
#define DHsz 64
#define Msz (Bsz * Tsz)   // 8192
#define K2 1536           // stored K width of [hi|lo] buffers
#define QSCALE 11.5415603f  // 8 * log2(e): softmax via exp2

typedef __attribute__((ext_vector_type(8))) short short8;
typedef __attribute__((ext_vector_type(4))) float floatx4;

#if __has_builtin(__builtin_amdgcn_exp2f)
#define EXP2(x) __builtin_amdgcn_exp2f(x)
#else
#define EXP2(x) exp2f(x)
#endif

typedef const __attribute__((address_space(1))) unsigned int* gas1;
typedef __attribute__((address_space(3))) unsigned int* las3;
// async global->LDS DMA, 16 B/lane, lane i lands at ldsbase + 16*i (wave-linear)
__device__ __forceinline__ void dma16(const unsigned short* g, unsigned short* l) {
  __builtin_amdgcn_global_load_lds((gas1)g, (las3)l, 16, 0, 0);
}

__device__ __forceinline__ unsigned short f2bf(float f) {
  union { float f; unsigned u; } v; v.f = f;
  unsigned u = v.u;
  unsigned r = u + 0x7fffu + ((u >> 16) & 1u);  // RNE; finite inputs
  return (unsigned short)(r >> 16);
}
__device__ __forceinline__ float bf2f(unsigned short h) {
  union { unsigned u; float f; } v; v.u = ((unsigned)h) << 16; return v.f;
}
__device__ __forceinline__ unsigned pk_bf2(float a, float b) {
  union { __hip_bfloat162 b2; unsigned u; } cv;
  cv.b2 = __float22bfloat162_rn(make_float2(a, b));  // v_cvt_pk_bf16_f32
  return cv.u;
}

// XOR-swizzled tile addressing: tile stored as [rows][8 granules of 8 shorts],
// physical granule = g ^ (row&7). DMA writes linear; reads swizzle. 0 conflicts (R6).
#define TREAD(arr, row, s) \
  (*reinterpret_cast<const short8*>(&(arr)[((row) << 6) + ((((s) * 4 + quad) ^ ((row) & 7)) << 3)]))

// ---------------- split kernels: f32 -> row-interleaved [hi768|lo768] ----------------
__global__ void split_x(const float* __restrict__ src,
                        unsigned short* __restrict__ dst) {
  int i = (blockIdx.x * blockDim.x + threadIdx.x) * 4;   // exact cover of Msz*Dsz
  int row = i / Dsz, col = i % Dsz;
  float4 v = *reinterpret_cast<const float4*>(src + i);
  ushort4 h, l;
  h.x = f2bf(v.x); l.x = f2bf(v.x - bf2f(h.x));
  h.y = f2bf(v.y); l.y = f2bf(v.y - bf2f(h.y));
  h.z = f2bf(v.z); l.z = f2bf(v.z - bf2f(h.z));
  h.w = f2bf(v.w); l.w = f2bf(v.w - bf2f(h.w));
  unsigned short* base = dst + (size_t)row * K2 + col;
  *reinterpret_cast<ushort4*>(base) = h;
  *reinterpret_cast<ushort4*>(base + Dsz) = l;
}

// w_qkv [2304][768] -> permuted rows r' = kk*768 + h*64 + d (src row d*36+kk*12+h),
// row-interleaved [hi768|lo768]
__global__ void split_w(const float* __restrict__ src,
                        unsigned short* __restrict__ dst) {
  int i = (blockIdx.x * blockDim.x + threadIdx.x) * 4;   // exact cover of 3*Dsz*Dsz
  int rp = i / Dsz, c = i % Dsz;
  int kk = rp / Dsz;
  int rem = rp - kk * Dsz;
  int h = rem >> 6, d = rem & 63;
  const float* s = src + (size_t)(d * 36 + kk * 12 + h) * Dsz + c;
  float4 v = *reinterpret_cast<const float4*>(s);
  ushort4 hh, ll;
  hh.x = f2bf(v.x); ll.x = f2bf(v.x - bf2f(hh.x));
  hh.y = f2bf(v.y); ll.y = f2bf(v.y - bf2f(hh.y));
  hh.z = f2bf(v.z); ll.z = f2bf(v.z - bf2f(hh.z));
  hh.w = f2bf(v.w); ll.w = f2bf(v.w - bf2f(hh.w));
  unsigned short* base = dst + (size_t)rp * K2 + c;
  *reinterpret_cast<ushort4*>(base) = hh;
  *reinterpret_cast<ushort4*>(base + Dsz) = ll;
}

__global__ void cvt_f32_bf16(const float* __restrict__ src,
                             unsigned short* __restrict__ dst, int n) {
  int i = (blockIdx.x * blockDim.x + threadIdx.x) * 4;
  int stride = gridDim.x * blockDim.x * 4;
  for (; i < n; i += stride) {
    float4 v = *reinterpret_cast<const float4*>(src + i);
    ushort4 o;
    o.x = f2bf(v.x); o.y = f2bf(v.y); o.z = f2bf(v.z); o.w = f2bf(v.w);
    *reinterpret_cast<ushort4*>(dst + i) = o;
  }
}

// ---------------- QKV GEMM: staged A+B, XCD-exclusive A-tiles ----------------
// 1D grid 2304. xcd = bid&7 owns mt128 in [xcd*8, xcd*8+8): A fetched ONCE per XCD
// (3 MB, L2-resident). mt-fastest within XCD: 8 co-resident blocks share each B-tile.
// Q/K: Xh.Wh + Xh.Wl + Xl.Wh; V: Xh.Wh only.
__launch_bounds__(256, 3)
__global__ void gemm_qkv(const unsigned short* __restrict__ xs,
                         const unsigned short* __restrict__ wsb,
                         unsigned short* __restrict__ Qhp,
                         unsigned short* __restrict__ Qlp,
                         unsigned short* __restrict__ Khp,
                         unsigned short* __restrict__ Klp,
                         unsigned short* __restrict__ Vtp) {
  __shared__ unsigned short Ah[128 * 64], Al[128 * 64];   // 16 KB each, swizzled
  __shared__ unsigned short Bh[64 * 64],  Bl[64 * 64];    // 8 KB each (48 KB total)
  const int bid = blockIdx.x;          // 0..2303
  const int xcd = bid & 7;
  const int slot = bid >> 3;           // 0..287
  const int nblk = slot >> 3;          // 0..35
  const int mt128 = xcd * 8 + (slot & 7);   // XCD-exclusive M tiles
  const int kk = nblk / 12;            // 0:Q 1:K 2:V
  const int h  = nblk % 12;
  const int tid = threadIdx.x;
  const int w = tid >> 6, lane = tid & 63, l16 = lane & 15, quad = lane >> 4;
  const int lrow = lane >> 3;              // 0..7
  const int lgl  = (lane & 7) ^ lrow;      // XOR granule

  floatx4 acc[2][4];
#pragma unroll
  for (int mt = 0; mt < 2; ++mt)
#pragma unroll
    for (int nt = 0; nt < 4; ++nt) acc[mt][nt] = (floatx4){0.f, 0.f, 0.f, 0.f};

  const size_t abase = (size_t)(mt128 * 128) * K2;                 // hi at +0, lo at +Dsz
  const size_t bbase = (size_t)(kk * Dsz + h * 64) * K2;

  for (int kc = 0; kc < Dsz; kc += 64) {
    __syncthreads();   // prev tile's readers done
#pragma unroll
    for (int j = 0; j < 4; ++j) {          // A: 16 KB (+16 KB lo), 4(+4) insts/wave
      const int R0 = w * 32 + j * 8;
      const size_t g = abase + (size_t)(R0 + lrow) * K2 + kc + lgl * 8;
      dma16(xs + g, &Ah[R0 * 64]);
      if (kk != 2) dma16(xs + g + Dsz, &Al[R0 * 64]);
    }
#pragma unroll
    for (int j = 0; j < 2; ++j) {          // B: 8 KB (+8 KB lo), 2(+2) insts/wave
      const int R0 = w * 16 + j * 8;
      const size_t g = bbase + (size_t)(R0 + lrow) * K2 + kc + lgl * 8;
      dma16(wsb + g, &Bh[R0 * 64]);
      if (kk != 2) dma16(wsb + g + Dsz, &Bl[R0 * 64]);
    }
    __syncthreads();   // vmcnt drain: staged data visible
#pragma unroll
    for (int s = 0; s < 2; ++s) {
      short8 ah[2], al[2];
#pragma unroll
      for (int mt = 0; mt < 2; ++mt) ah[mt] = TREAD(Ah, w * 32 + mt * 16 + l16, s);
      if (kk != 2) {
#pragma unroll
        for (int mt = 0; mt < 2; ++mt) al[mt] = TREAD(Al, w * 32 + mt * 16 + l16, s);
      }
#pragma unroll
      for (int nt = 0; nt < 4; ++nt) {
        short8 bh = TREAD(Bh, nt * 16 + l16, s);
#pragma unroll
        for (int mt = 0; mt < 2; ++mt)
          acc[mt][nt] = __builtin_amdgcn_mfma_f32_16x16x32_bf16(ah[mt], bh, acc[mt][nt], 0, 0, 0);
        if (kk != 2) {
          short8 bl = TREAD(Bl, nt * 16 + l16, s);
#pragma unroll
          for (int mt = 0; mt < 2; ++mt) {
            acc[mt][nt] = __builtin_amdgcn_mfma_f32_16x16x32_bf16(ah[mt], bl, acc[mt][nt], 0, 0, 0);
            acc[mt][nt] = __builtin_amdgcn_mfma_f32_16x16x32_bf16(al[mt], bh, acc[mt][nt], 0, 0, 0);
          }
        }
      }
    }
  }
#pragma unroll
  for (int mt = 0; mt < 2; ++mt) {
    const int mbase = mt128 * 128 + w * 32 + mt * 16 + quad * 4;
    const int b = mbase >> 11;   // tiles never cross batch boundary
    const size_t hoff = (size_t)(b * Hsz + h) * Tsz * DHsz;
    const int t0 = mbase & (Tsz - 1);
    if (kk == 2) {
      unsigned short* dst = Vtp + hoff;   // [dh][t]
#pragma unroll
      for (int nt = 0; nt < 4; ++nt) {
        int d = nt * 16 + l16;
        uint2 pk;
        pk.x = pk_bf2(acc[mt][nt][0], acc[mt][nt][1]);
        pk.y = pk_bf2(acc[mt][nt][2], acc[mt][nt][3]);
        *reinterpret_cast<uint2*>(&dst[(size_t)d * Tsz + t0]) = pk;
      }
    } else {
      const float sc = (kk == 0) ? QSCALE : 1.0f;   // fold 8*log2e into Q
      unsigned short* dh_ = ((kk == 0) ? Qhp : Khp) + hoff;
      unsigned short* dl_ = ((kk == 0) ? Qlp : Klp) + hoff;
#pragma unroll
      for (int nt = 0; nt < 4; ++nt) {
        int d = nt * 16 + l16;
#pragma unroll
        for (int r = 0; r < 4; ++r) {
          float v = acc[mt][nt][r] * sc;
          unsigned short hv = f2bf(v);
          dh_[(size_t)(t0 + r) * DHsz + d] = hv;
          dl_[(size_t)(t0 + r) * DHsz + d] = f2bf(v - bf2f(hv));
        }
      }
    }
  }
}

// ---------------- fused flash attention (R8/R9-verified, ~119 us) ----------------
__launch_bounds__(256, 3)
__global__ void attn(const unsigned short* __restrict__ Qhp,
                     const unsigned short* __restrict__ Qlp,
                     const unsigned short* __restrict__ Khp,
                     const unsigned short* __restrict__ Klp,
                     const unsigned short* __restrict__ Vtp,
                     unsigned short* __restrict__ Ob) {
  __shared__ unsigned short Ksh[64 * 64], Ksl[64 * 64], Vs[64 * 64];  // swizzled tiles
  __shared__ unsigned short plT[4][2][16][68];   // 68-pad: proven 0-conflict writes
  const int bid = blockIdx.x;          // 0..767
  const int xcd = bid & 7, slot = bid >> 3;
  const int bh = xcd * 6 + (slot >> 4);
  const int qt = slot & 15;
  const int tid = threadIdx.x;
  const int w = tid >> 6, lane = tid & 63, l16 = lane & 15, quad = lane >> 4;
  const int lrow = lane >> 3;
  const int lgl  = (lane & 7) ^ lrow;
  const size_t hoff = (size_t)bh * Tsz * DHsz;
  const unsigned short* Kh = Khp + hoff;
  const unsigned short* Kl = Klp + hoff;
  const unsigned short* Vt = Vtp + hoff;   // [dh][t]

  // Q B-frags (pre-scaled by 8*log2e)
  short8 qh[2][2], ql[2][2];
#pragma unroll
  for (int mt = 0; mt < 2; ++mt) {
    const size_t qoff = hoff + (size_t)(qt * 128 + w * 32 + mt * 16 + l16) * DHsz + quad * 8;
    qh[mt][0] = *reinterpret_cast<const short8*>(Qhp + qoff);
    qh[mt][1] = *reinterpret_cast<const short8*>(Qhp + qoff + 32);
    ql[mt][0] = *reinterpret_cast<const short8*>(Qlp + qoff);
    ql[mt][1] = *reinterpret_cast<const short8*>(Qlp + qoff + 32);
  }

  floatx4 Of[2][4];
#pragma unroll
  for (int mt = 0; mt < 2; ++mt)
#pragma unroll
    for (int nt = 0; nt < 4; ++nt) Of[mt][nt] = (floatx4){0.f, 0.f, 0.f, 0.f};
  float m_i[2] = {-1e30f, -1e30f};
  float l_i[2] = {0.f, 0.f};

  for (int kt = 0; kt < Tsz; kt += 64) {
    __syncthreads();   // prev tile's readers done
#pragma unroll
    for (int j = 0; j < 2; ++j) {       // each array 8 KB = 2 insts/wave
      const int R0 = w * 16 + j * 8;
      dma16(Kh + (size_t)(kt + R0 + lrow) * DHsz + lgl * 8, &Ksh[R0 * 64]);
      dma16(Kl + (size_t)(kt + R0 + lrow) * DHsz + lgl * 8, &Ksl[R0 * 64]);
      dma16(Vt + (size_t)(R0 + lrow) * Tsz + kt + lgl * 8,  &Vs[R0 * 64]);
    }
    __syncthreads();   // vmcnt drain: staged tiles visible

    // S^T = K Q^T, double-bf16 (Kh*Qh + Kl*Qh + Kh*Ql)
    floatx4 S[2][4];
#pragma unroll
    for (int mt = 0; mt < 2; ++mt)
#pragma unroll
      for (int nt = 0; nt < 4; ++nt) S[mt][nt] = (floatx4){0.f, 0.f, 0.f, 0.f};
#pragma unroll
    for (int s = 0; s < 2; ++s) {
#pragma unroll
      for (int nt = 0; nt < 4; ++nt) {
        short8 kf_h = TREAD(Ksh, nt * 16 + l16, s);
        short8 kf_l = TREAD(Ksl, nt * 16 + l16, s);
        S[0][nt] = __builtin_amdgcn_mfma_f32_16x16x32_bf16(kf_h, qh[0][s], S[0][nt], 0, 0, 0);
        S[0][nt] = __builtin_amdgcn_mfma_f32_16x16x32_bf16(kf_l, qh[0][s], S[0][nt], 0, 0, 0);
        S[0][nt] = __builtin_amdgcn_mfma_f32_16x16x32_bf16(kf_h, ql[0][s], S[0][nt], 0, 0, 0);
        S[1][nt] = __builtin_amdgcn_mfma_f32_16x16x32_bf16(kf_h, qh[1][s], S[1][nt], 0, 0, 0);
        S[1][nt] = __builtin_amdgcn_mfma_f32_16x16x32_bf16(kf_l, qh[1][s], S[1][nt], 0, 0, 0);
        S[1][nt] = __builtin_amdgcn_mfma_f32_16x16x32_bf16(kf_h, ql[1][s], S[1][nt], 0, 0, 0);
      }
    }

    // per-lane online softmax in exp2 domain (q = l16; keys in regs+quads)
#pragma unroll
    for (int mt = 0; mt < 2; ++mt) {
      float mx = -1e30f;
#pragma unroll
      for (int nt = 0; nt < 4; ++nt)
#pragma unroll
        for (int r = 0; r < 4; ++r) mx = fmaxf(mx, S[mt][nt][r]);
      mx = fmaxf(mx, __shfl_xor(mx, 16));
      mx = fmaxf(mx, __shfl_xor(mx, 32));
      float mnew = fmaxf(m_i[mt], mx);
      float alpha = EXP2(m_i[mt] - mnew);
      m_i[mt] = mnew;
      float ls = 0.f;
#pragma unroll
      for (int nt = 0; nt < 4; ++nt) {
        float p0 = EXP2(S[mt][nt][0] - mnew);
        float p1 = EXP2(S[mt][nt][1] - mnew);
        float p2 = EXP2(S[mt][nt][2] - mnew);
        float p3 = EXP2(S[mt][nt][3] - mnew);
        ls += (p0 + p1) + (p2 + p3);
        uint2 pk;
        pk.x = pk_bf2(p0, p1);
        pk.y = pk_bf2(p2, p3);
        *reinterpret_cast<uint2*>(&plT[w][mt][l16][nt * 16 + quad * 4]) = pk;
      }
      l_i[mt] = l_i[mt] * alpha + ls;
#pragma unroll
      for (int nt = 0; nt < 4; ++nt) {
        Of[mt][nt][0] *= alpha; Of[mt][nt][1] *= alpha;
        Of[mt][nt][2] *= alpha; Of[mt][nt][3] *= alpha;
      }
    }

    // O^T += V^T @ P^T (wave-local LDS RAW; wave-synchronous)
    short8 pf[2][2];
#pragma unroll
    for (int s = 0; s < 2; ++s) {
      pf[0][s] = *reinterpret_cast<const short8*>(&plT[w][0][l16][s * 32 + quad * 8]);
      pf[1][s] = *reinterpret_cast<const short8*>(&plT[w][1][l16][s * 32 + quad * 8]);
    }
#pragma unroll
    for (int nt = 0; nt < 4; ++nt) {
#pragma unroll
      for (int s = 0; s < 2; ++s) {
        short8 vf = TREAD(Vs, nt * 16 + l16, s);
        Of[0][nt] = __builtin_amdgcn_mfma_f32_16x16x32_bf16(vf, pf[0][s], Of[0][nt], 0, 0, 0);
        Of[1][nt] = __builtin_amdgcn_mfma_f32_16x16x32_bf16(vf, pf[1][s], Of[1][nt], 0, 0, 0);
      }
    }
  }

  // epilogue: O[b][t][h*64+dh]; dh = nt*16 + quad*4 + reg, t = ... + l16
  const int b = bh / Hsz, h = bh % Hsz;
#pragma unroll
  for (int mt = 0; mt < 2; ++mt) {
    float ls = l_i[mt];
    ls += __shfl_xor(ls, 16);
    ls += __shfl_xor(ls, 32);
    float inv = 1.0f / ls;
    int t = qt * 128 + w * 32 + mt * 16 + l16;
    unsigned short* orow = Ob + (size_t)(b * Tsz + t) * Dsz + h * DHsz;
#pragma unroll
    for (int nt = 0; nt < 4; ++nt) {
      uint2 pk;
      pk.x = pk_bf2(Of[mt][nt][0] * inv, Of[mt][nt][1] * inv);
      pk.y = pk_bf2(Of[mt][nt][2] * inv, Of[mt][nt][3] * inv);
      *reinterpret_cast<uint2*>(&orow[nt * 16 + quad * 4]) = pk;
    }
  }
}

// ---------------- output GEMM: staged A+B, XCD-exclusive A-tiles ----------------
// 1D grid 384. xcd = bid&7 owns mt128 in [xcd*8, xcd*8+8); mt-fastest within XCD.
__launch_bounds__(256, 3)
__global__ void gemm_out(const unsigned short* __restrict__ ob,
                         const unsigned short* __restrict__ wb,
                         float* __restrict__ out) {
  __shared__ unsigned short As[128 * 64];   // swizzled
  __shared__ unsigned short Bs[128 * 64];
  const int bid = blockIdx.x;          // 0..383
  const int xcd = bid & 7;
  const int slot = bid >> 3;           // 0..47
  const int n0 = (slot >> 3) * 128;    // 0..640
  const int mt128 = xcd * 8 + (slot & 7);
  const int tid = threadIdx.x;
  const int w = tid >> 6, lane = tid & 63, l16 = lane & 15, quad = lane >> 4;
  const int lrow = lane >> 3;
  const int lgl  = (lane & 7) ^ lrow;

  floatx4 acc[2][8];
#pragma unroll
  for (int mt = 0; mt < 2; ++mt)
#pragma unroll
    for (int nt = 0; nt < 8; ++nt) acc[mt][nt] = (floatx4){0.f, 0.f, 0.f, 0.f};

  const size_t abase = (size_t)(mt128 * 128) * Dsz;
  const size_t bbase = (size_t)n0 * Dsz;

  for (int kc = 0; kc < Dsz; kc += 64) {
    __syncthreads();
#pragma unroll
    for (int j = 0; j < 4; ++j) {
      const int R0 = w * 32 + j * 8;
      dma16(ob + abase + (size_t)(R0 + lrow) * Dsz + kc + lgl * 8, &As[R0 * 64]);
    }
#pragma unroll
    for (int j = 0; j < 4; ++j) {
      const int R0 = w * 32 + j * 8;
      dma16(wb + bbase + (size_t)(R0 + lrow) * Dsz + kc + lgl * 8, &Bs[R0 * 64]);
    }
    __syncthreads();
#pragma unroll
    for (int s = 0; s < 2; ++s) {
      short8 a[2];
#pragma unroll
      for (int mt = 0; mt < 2; ++mt) a[mt] = TREAD(As, w * 32 + mt * 16 + l16, s);
#pragma unroll
      for (int nt = 0; nt < 8; ++nt) {
        short8 b = TREAD(Bs, nt * 16 + l16, s);
#pragma unroll
        for (int mt = 0; mt < 2; ++mt)
          acc[mt][nt] = __builtin_amdgcn_mfma_f32_16x16x32_bf16(a[mt], b, acc[mt][nt], 0, 0, 0);
      }
    }
  }
#pragma unroll
  for (int mt = 0; mt < 2; ++mt) {
    const int mbase = mt128 * 128 + w * 32 + mt * 16 + quad * 4;
#pragma unroll
    for (int nt = 0; nt < 8; ++nt) {
      int n = n0 + nt * 16 + l16;
#pragma unroll
      for (int r = 0; r < 4; ++r) {
        out[(size_t)(mbase + r) * Dsz + n] = acc[mt][nt][r];
      }
    }
  }
}

// ---------------- launch ----------------
extern "C" void kernel_launch(void* const* d_in, const int* in_sizes, int n_in,
                              void* d_out, int out_size, void* d_ws, size_t ws_size,
                              hipStream_t stream) {
  const float* x     = (const float*)d_in[0];   // [4,2048,768]
  const float* w_qkv = (const float*)d_in[1];   // [2304,768]
  const float* w_out = (const float*)d_in[2];   // [768,768]
  float* out = (float*)d_out;                   // [4,2048,768]

  unsigned short* ws = (unsigned short*)d_ws;
  const size_t nXs = (size_t)Msz * K2;                // 12582912 (x hi|lo)
  const size_t nWs = (size_t)3 * Dsz * K2;            // 3538944 (w hi|lo)
  const size_t nWo = (size_t)Dsz * Dsz;               // 589824
  const size_t nHd = (size_t)Bsz * Hsz * Tsz * DHsz;  // 6291456

  unsigned short* xs  = ws;
  unsigned short* wsb = xs + nXs;
  unsigned short* wob = wsb + nWs;
  unsigned short* Qhp = wob + nWo;
  unsigned short* Qlp = Qhp + nHd;
  unsigned short* Khp = Qlp + nHd;
  unsigned short* Klp = Khp + nHd;
  unsigned short* Vtp = Klp + nHd;
  unsigned short* Ob  = xs;   // xs dead after gemm_qkv
  // peak ws use ~96.3 MB

  split_x<<<(int)(nXs / 2 / 1024), 256, 0, stream>>>(x, xs);
  split_w<<<(int)(nWs / 2 / 1024), 256, 0, stream>>>(w_qkv, wsb);
  cvt_f32_bf16<<<256, 256, 0, stream>>>(w_out, wob, (int)nWo);
  gemm_qkv<<<2304, 256, 0, stream>>>(xs, wsb, Qhp, Qlp, Khp, Klp, Vtp);
  attn<<<768, 256, 0, stream>>>(Qhp, Qlp, Khp, Klp, Vtp, Ob);
  gemm_out<<<384, 256, 0, stream>>>(Ob, wob, out);
}